// Round 1
// baseline (342.896 us; speedup 1.0000x reference)
//
#include <hip/hip_runtime.h>
#include <hip/hip_bf16.h>

#define B_DIM 256
#define T_DIM 512
#define K_DIM 128

// One block per (pass, batch-row). pass 0 = unclamped, pass 1 = gold-clamped.
// Thread layout: tid = jq*128 + k ; k in [0,128), jq in [0,4).
// Thread (k,jq) holds E[j][k] = exp(trans[j][k]) for j in [32*jq, 32*jq+32) in registers.
// State per step: pbuf[k] = exp(alpha[k] - m) in LDS; m scalar (tracked by jq==0 threads).
__global__ __launch_bounds__(512) void crf_pass_kernel(
    const float* __restrict__ tw,      // [B,T,K]
    const float* __restrict__ trans,   // [K,K]
    const int*   __restrict__ gold,    // [B,T]
    const int*   __restrict__ lengths, // [B]
    float*       __restrict__ wsv)     // [2*B] logZ per (pass,b)
{
    const int bid = blockIdx.x;
    const int b = bid & (B_DIM - 1);
    const bool clamp = bid >= B_DIM;
    const int tid = threadIdx.x;
    const int k = tid & (K_DIM - 1);
    const int jq = tid >> 7;           // 0..3, wave-uniform

    __shared__ __align__(16) float pbuf[K_DIM];
    __shared__ float part[4][K_DIM];

    // ---- load E fragment into registers ----
    float Ereg[32];
#pragma unroll
    for (int i = 0; i < 32; ++i)
        Ereg[i] = __expf(trans[(jq * 32 + i) * K_DIM + k]);

    const int len = lengths[b];
    const float* twb = tw + (size_t)b * T_DIM * K_DIM;
    const int* goldb = gold + b * T_DIM;

    // ---- t = 0 init ----
    float m;
    {
        float e_k = twb[k];
        float e_0 = twb[0];
        int g = clamp ? goldb[0] : -1;
        m = e_0;
        float p = __expf(e_k - e_0);
        if (g >= 0 && g != k) p = 0.0f;
        if (jq == 0) pbuf[k] = p;
    }
    __syncthreads();

    // ---- prefetch steps 1..4 (only jq==0 threads consume these) ----
    float curE[4], cur0[4]; int curG[4];
#pragma unroll
    for (int i = 0; i < 4; ++i) {
        int t = 1 + i; if (t > T_DIM - 1) t = T_DIM - 1;
        curE[i] = (jq == 0) ? twb[t * K_DIM + k] : 0.0f;
        cur0[i] = (jq == 0) ? twb[t * K_DIM] : 0.0f;
        curG[i] = (jq == 0 && clamp) ? goldb[t] : -1;
    }

    for (int tbase = 1; tbase < len; tbase += 4) {
        // issue prefetch for next chunk (addresses clamped; values unused past len)
        float nxtE[4], nxt0[4]; int nxtG[4];
#pragma unroll
        for (int i = 0; i < 4; ++i) {
            int t = tbase + 4 + i; if (t > T_DIM - 1) t = T_DIM - 1;
            nxtE[i] = (jq == 0) ? twb[t * K_DIM + k] : 0.0f;
            nxt0[i] = (jq == 0) ? twb[t * K_DIM] : 0.0f;
            nxtG[i] = (jq == 0 && clamp) ? goldb[t] : -1;
        }

#pragma unroll
        for (int i = 0; i < 4; ++i) {
            const int t = tbase + i;
            const bool live = (t < len);   // block-uniform
            if (live) {
                // phase A: partial matvec s_k(jq) = sum over 32 j's
                float a0 = 0.f, a1 = 0.f, a2 = 0.f, a3 = 0.f;
                const float4* pv = (const float4*)&pbuf[jq * 32];
#pragma unroll
                for (int q = 0; q < 8; ++q) {
                    float4 pj = pv[q];
                    a0 = fmaf(pj.x, Ereg[4 * q + 0], a0);
                    a1 = fmaf(pj.y, Ereg[4 * q + 1], a1);
                    a2 = fmaf(pj.z, Ereg[4 * q + 2], a2);
                    a3 = fmaf(pj.w, Ereg[4 * q + 3], a3);
                }
                part[jq][k] = (a0 + a1) + (a2 + a3);
            }
            __syncthreads();
            if (live && jq == 0) {
                float s_k = ((part[0][k] + part[1][k]) + (part[2][k] + part[3][k]));
                float s_0 = ((part[0][0] + part[1][0]) + (part[2][0] + part[3][0]));
                float e0 = cur0[i], ek = curE[i]; int g = curG[i];
                m += __logf(s_0) + e0;
                float p = s_k * __builtin_amdgcn_rcpf(s_0) * __expf(ek - e0);
                if (g >= 0 && g != k) p = 0.0f;
                pbuf[k] = p;
            }
            __syncthreads();
        }
#pragma unroll
        for (int i = 0; i < 4; ++i) { curE[i] = nxtE[i]; cur0[i] = nxt0[i]; curG[i] = nxtG[i]; }
    }

    // ---- final: logZ = m + log(sum_k p[k]) ----
    if (tid < 64) {
        float v = pbuf[tid] + pbuf[tid + 64];
#pragma unroll
        for (int off = 32; off; off >>= 1) v += __shfl_xor(v, off);
        if (tid == 0) wsv[bid] = m + __logf(v);
    }
}

__global__ void crf_finalize(const float* __restrict__ wsv, float* __restrict__ out)
{
    const int tid = threadIdx.x;   // 256 threads, one per batch row
    float d = wsv[tid] - wsv[B_DIM + tid];
#pragma unroll
    for (int off = 32; off; off >>= 1) d += __shfl_xor(d, off);
    __shared__ float red[4];
    if ((tid & 63) == 0) red[tid >> 6] = d;
    __syncthreads();
    if (tid == 0) out[0] = (red[0] + red[1] + red[2] + red[3]) * (1.0f / (float)B_DIM);
}

extern "C" void kernel_launch(void* const* d_in, const int* in_sizes, int n_in,
                              void* d_out, int out_size, void* d_ws, size_t ws_size,
                              hipStream_t stream)
{
    const float* tw      = (const float*)d_in[0];
    const float* trans   = (const float*)d_in[1];
    const int*   gold    = (const int*)d_in[2];
    const int*   lengths = (const int*)d_in[3];
    float* wsv = (float*)d_ws;          // 2*B floats
    float* out = (float*)d_out;

    crf_pass_kernel<<<2 * B_DIM, 512, 0, stream>>>(tw, trans, gold, lengths, wsv);
    crf_finalize<<<1, B_DIM, 0, stream>>>(wsv, out);
}